// Round 2
// baseline (333.509 us; speedup 1.0000x reference)
//
#include <hip/hip_runtime.h>

#define NN 4096      // reviews
#define LL 128       // tokens
#define DD 200       // word dim
#define AA 32        // aspects
#define NEG 5
#define BB 1024      // users/items

// workspace layout (float offsets)
#define WS_RS    0
#define WS_ACC   (NN*DD)   // [0]=J_sum [1]=U_mean [2]=RL_sum [8]=done(int)

// ---------------- DPP reductions (VALU, no DS pipe) -------------------------
template<int C, int RM>
__device__ __forceinline__ float dpp_add(float v){
  int t = __builtin_amdgcn_update_dpp(0, __float_as_int(v), C, RM, 0xf, false);
  return v + __int_as_float(t);
}
template<int C, int RM>
__device__ __forceinline__ float dpp_fmax(float v){
  int t = __builtin_amdgcn_update_dpp(__float_as_int(-3.0e38f), __float_as_int(v),
                                      C, RM, 0xf, false);
  return fmaxf(v, __int_as_float(t));
}
// full 64-lane sum; valid in lane 63
__device__ __forceinline__ float sum64(float v){
  v = dpp_add<0xB1, 0xF>(v);
  v = dpp_add<0x4E, 0xF>(v);
  v = dpp_add<0x124,0xF>(v);
  v = dpp_add<0x128,0xF>(v);
  v = dpp_add<0x142,0xA>(v);
  v = dpp_add<0x143,0xC>(v);
  return v;
}
__device__ __forceinline__ float max64(float v){
  v = dpp_fmax<0xB1, 0xF>(v);
  v = dpp_fmax<0x4E, 0xF>(v);
  v = dpp_fmax<0x124,0xF>(v);
  v = dpp_fmax<0x128,0xF>(v);
  v = dpp_fmax<0x142,0xA>(v);
  v = dpp_fmax<0x143,0xC>(v);
  return v;
}
// 8-lane (octet) sum: valid at lanes j%8==0
__device__ __forceinline__ float sum8(float v){
  v = dpp_add<0xB1, 0xF>(v);
  v = dpp_add<0x4E, 0xF>(v);
  v = dpp_add<0x124,0xF>(v);
  return v;
}
__device__ __forceinline__ float rdlane(float v, int l){
  return __int_as_float(__builtin_amdgcn_readlane(__float_as_int(v), l));
}
__device__ __forceinline__ float dot4(float4 a, float4 b){
  return a.x*b.x + a.y*b.y + a.z*b.z + a.w*b.w;
}
// LDS byte-address swizzle: XOR bits 9-11 into bits 4-6 (keeps b128 alignment)
__device__ __forceinline__ int swz(int a){ return a ^ (((a >> 9) & 7) << 4); }

// ---- main per-review kernel ------------------------------------------------
// 512 threads (8 waves), one review per block, 1 block/CU (LDS ~106 KB).
// e_w slab (128x200 f32 = 102.4 KB) staged in LDS during dx phase, re-used by
// the z phase (flat reshape is the SAME linear buffer). Per-wave slab:
// wave w owns rows [16w,16w+16) == flat floats [3200w, 3200w+3200)
// == z outputs d2 in [25w, 25w+25).  XOR-swizzled to kill the 512B-stride
// 8-way bank conflict on the z-phase ds_read_b128.
__global__ __launch_bounds__(512, 2)
void k_main(const int* __restrict__ hist, const float* __restrict__ rev_pos,
            const float* __restrict__ rev_neg, const float* __restrict__ word_emb,
            const float* __restrict__ M_w, const float* __restrict__ W_w,
            const float* __restrict__ W_b, const float* __restrict__ T_w,
            float* __restrict__ rs_out, float* __restrict__ acc)
{
  __shared__ __align__(16) float smem[26496];
  float* slab = smem;            // [25600] e_w flat slab (per-wave 3200-float regions)
  float* ypart= smem;            // [1600] aliases slab (dead before slab writes)
  float* y_l  = smem + 25600;    // [200]
  float* dxax = smem + 25800;    // [128]
  float* zsm  = smem + 25928;    // [200]
  float* r_l  = smem + 26128;    // [200] holds rp first, r_s later
  float* lsps = smem + 26328;    // [32]
  float* sc   = smem + 26360;    // [8]
  int*   hrowl= (int*)(smem + 26368); // [128]

  const int n = blockIdx.x;
  const int t = threadIdx.x;
  const int w = t >> 6, j = t & 63;
  const int wu = __builtin_amdgcn_readfirstlane(w);

  if (t < DD) r_l[t] = rev_pos[(size_t)n * DD + t];
  if (t < LL) hrowl[t] = hist[(size_t)n * LL + t];
  __syncthreads();

  // ---- y = rp @ M, split-K across 8 waves: wave w covers dk in [25w,25w+25)
  if (j < 50){
    float ax = 0.f, ay = 0.f, az = 0.f, aw = 0.f;
    const float* Mb = M_w + (25 * wu) * DD + 4 * j;
    const float* rb = r_l + 25 * wu;
#pragma unroll 5
    for (int dk = 0; dk < 25; ++dk){
      float rv = rb[dk];
      float4 m4 = *(const float4*)(Mb + dk * DD);
      ax = fmaf(rv, m4.x, ax); ay = fmaf(rv, m4.y, ay);
      az = fmaf(rv, m4.z, az); aw = fmaf(rv, m4.w, aw);
    }
    float4 o; o.x = ax; o.y = ay; o.z = az; o.w = aw;
    *(float4*)(ypart + wu * 200 + 4 * j) = o;
  }
  __syncthreads();
  float yacc = 0.f;
  if (t < DD){
#pragma unroll
    for (int p = 0; p < 8; ++p) yacc += ypart[200 * p + t];
  }
  __syncthreads();                 // ypart reads done before slab overwrites
  if (t < DD) y_l[t] = yacc;
  __syncthreads();

  // ---- dx[l] = dot(e_w[l], y): wave w owns rows [16w,16w+16) --------------
  // Loads also staged into the per-wave LDS slab (swizzled) for the z phase.
  {
    float4 y4 = make_float4(0.f, 0.f, 0.f, 0.f);
    int col = 0;
    if (j < 50){ y4 = *(const float4*)(y_l + 4 * j); col = 4 * j; }
    const int* hrow_g = hist + (size_t)n * LL + 16 * wu;   // uniform base
    char* slabW = (char*)(slab + wu * 3200);               // per-wave region
#pragma unroll
    for (int k8 = 0; k8 < 2; ++k8){
      int rows[8];
#pragma unroll
      for (int i = 0; i < 8; ++i) rows[i] = hrow_g[8 * k8 + i];   // s_load
      float4 g[8];
#pragma unroll
      for (int i = 0; i < 8; ++i)
        g[i] = *(const float4*)(word_emb + (size_t)rows[i] * DD + col);
#pragma unroll
      for (int i = 0; i < 8; ++i){
        if (j < 50){
          int wa = 800 * (8 * k8 + i) + 16 * j;      // local byte addr
          *(float4*)(slabW + swz(wa)) = g[i];
        }
        float v = sum64(dot4(g[i], y4));   // y4==0 for j>=50 lanes
        if (j == 63) dxax[16 * wu + 8 * k8 + i] = v;
      }
    }
  }
  __syncthreads();

  // ---- softmax over 128 logits (wave 0) -----------------------------------
  if (w == 0){
    float a0 = dxax[j], a1 = dxax[j + 64];
    float M = rdlane(max64(fmaxf(a0, a1)), 63);
    float e0 = __expf(a0 - M), e1 = __expf(a1 - M);
    float S = rdlane(sum64(e0 + e1), 63);
    float inv = 1.f / S;
    dxax[j] = e0 * inv; dxax[j + 64] = e1 * inv;
  }
  __syncthreads();

  // ---- z[d2] = sum_l flat[d2*128+l]*ax[l], flat slab now in LDS -----------
  // octet (8 lanes) per d2; wave w covers d2 in [25w,25w+25).
  {
    const int q = j & 7, oct = j >> 3;
    float4 ax0 = *(const float4*)(dxax +      4 * q);
    float4 ax1 = *(const float4*)(dxax + 32 + 4 * q);
    float4 ax2 = *(const float4*)(dxax + 64 + 4 * q);
    float4 ax3 = *(const float4*)(dxax + 96 + 4 * q);
    const char* baseW = (const char*)(slab + wu * 3200);
    const int qx = 16 * (q ^ oct);           // swizzled q-slot for off&7==oct
#pragma unroll
    for (int bp = 0; bp < 3; ++bp){
      int off = 8 * bp + oct;                // 0..23, off&7 == oct
      const char* p0 = baseW + 512 * off + qx;
      float4 g0 = *(const float4*)(p0);
      float4 g1 = *(const float4*)(p0 + 128);
      float4 g2 = *(const float4*)(p0 + 256);
      float4 g3 = *(const float4*)(p0 + 384);
      float v = sum8(dot4(g0,ax0) + dot4(g1,ax1) + dot4(g2,ax2) + dot4(g3,ax3));
      if (q == 0) zsm[25 * wu + off] = v;
    }
    { // off = 24 (off&7 == 0): all octets compute redundantly (broadcast reads)
      const char* p0 = baseW + 512 * 24 + 16 * q;
      float4 g0 = *(const float4*)(p0);
      float4 g1 = *(const float4*)(p0 + 128);
      float4 g2 = *(const float4*)(p0 + 256);
      float4 g3 = *(const float4*)(p0 + 384);
      float v = sum8(dot4(g0,ax0) + dot4(g1,ax1) + dot4(g2,ax2) + dot4(g3,ax3));
      if (j == 0) zsm[25 * wu + 24] = v;
    }
  }
  __syncthreads();

  // ---- aspect logits: wave w computes a = w*4..w*4+3 ----------------------
#pragma unroll
  for (int aa = 0; aa < 4; ++aa){
    int a = wu * 4 + aa;
    const float* Wr = W_w + a * DD;
    float p = zsm[j] * Wr[j] + zsm[j + 64] * Wr[j + 64] + zsm[j + 128] * Wr[j + 128];
    if (j < 8) p += zsm[j + 192] * Wr[j + 192];
    float v = sum64(p);
    if (j == 63) lsps[a] = v + W_b[a];
  }
  __syncthreads();

  // ---- softmax over 32 aspects (wave 0) -----------------------------------
  if (w == 0){
    float v = (j < 32) ? lsps[j] : -3.0e38f;
    float M = rdlane(max64(v), 63);
    float e = __expf(v - M);
    float S = rdlane(sum64(e), 63);
    if (j < 32) lsps[j] = e / S;
  }
  __syncthreads();

  // ---- r_s[d] = sum_a p[a]*T_w[d][a]: lane reads own 128B of T_w ----------
  if (t < DD){
    const float4* Tq = (const float4*)(T_w + t * AA);
    float a = 0.f;
#pragma unroll
    for (int q = 0; q < 8; ++q){
      float4 tv = Tq[q];
      a += lsps[4*q]*tv.x + lsps[4*q+1]*tv.y + lsps[4*q+2]*tv.z + lsps[4*q+3]*tv.w;
    }
    r_l[t] = a;
    rs_out[(size_t)n * DD + t] = a;
  }
  __syncthreads();

  // ---- c1 = cos(r, z) (wave 0, float4) ------------------------------------
  if (w == 0){
    float rr = 0, zz = 0, rz = 0;
    if (j < 50){
      float4 rv = *(float4*)(r_l + 4 * j);
      float4 zv = *(float4*)(zsm + 4 * j);
      rr = dot4(rv, rv); zz = dot4(zv, zv); rz = dot4(rv, zv);
    }
    rr = rdlane(sum64(rr), 63); zz = rdlane(sum64(zz), 63); rz = rdlane(sum64(rz), 63);
    if (j == 0){
      float nr = fmaxf(sqrtf(rr), 1e-12f);
      float nz = fmaxf(sqrtf(zz), 1e-12f);
      sc[0] = rz / (nr * nz);          // c1
      sc[1] = nr;
    }
  }
  __syncthreads();

  // ---- c2 over 5 negatives (waves 0..4), float4 ---------------------------
  if (w < NEG){
    const float* neg = rev_neg + ((size_t)n * NEG + w) * DD;
    float nn = 0, dr = 0;
    if (j < 50){
      float4 v = *(const float4*)(neg + 4 * j);
      float4 rv = *(float4*)(r_l + 4 * j);
      nn = dot4(v, v); dr = dot4(v, rv);
    }
    nn = rdlane(sum64(nn), 63); dr = rdlane(sum64(dr), 63);
    if (j == 0){
      float c2 = dr / (fmaxf(sqrtf(nn), 1e-12f) * sc[1]);
      sc[2 + w] = fmaxf(0.f, c2 - sc[0]);
    }
  }
  __syncthreads();
  if (t == 0) atomicAdd(&acc[0], sc[2] + sc[3] + sc[4] + sc[5] + sc[6]);
}

// ---- finalize helper -------------------------------------------------------
__device__ __forceinline__ void finalize(float* acc, float* out){
  float R = atomicAdd(&acc[2], 0.f) / (float)BB;        // coherent reads
  float J = atomicAdd(&acc[0], 0.f) / (float)(NN * NEG);
  float U = atomicAdd(&acc[1], 0.f);
  out[0] = R + U + J;
  out[1] = R;
  out[2] = U + J;
}

// ---- tail: blocks 0..BB-1 = segment-mean + rating; block BB = U loss -------
// seg ids are repeat(arange(B), H=16): block b owns entries [16b,16b+16).
__global__ __launch_bounds__(256)
void k_tail(const int* __restrict__ u_idx, const int* __restrict__ i_idx,
            const float* __restrict__ rs, const float* __restrict__ label,
            const float* __restrict__ T_w, float* __restrict__ acc,
            float* __restrict__ out){
  __shared__ __align__(16) float smem[6500];
  const int b = blockIdx.x, t = threadIdx.x, w = t >> 6, j = t & 63;

  if (b == BB){
    // ================= U loss =================
    float* Tl  = smem;          // [32][202]
    float* nrm = smem + 6464;
    float* wred= smem + 6496;
    for (int i = t; i < DD * AA; i += 256){
      int d = i >> 5, a = i & 31;
      Tl[a * 202 + d] = T_w[i];
    }
    __syncthreads();
    if (t < AA){
      float s = 0.f;
      for (int d = 0; d < DD; d += 2){
        float2 v = *(float2*)&Tl[t * 202 + d];
        s += v.x * v.x + v.y * v.y;
      }
      nrm[t] = fmaxf(sqrtf(s), 1e-12f);
    }
    __syncthreads();
    int a = t >> 3, b0 = (t & 7) * 4;
    float d0 = 0, d1 = 0, d2 = 0, d3 = 0;
    for (int d = 0; d < DD; d += 2){
      float2 va = *(float2*)&Tl[a * 202 + d];
      float2 v0 = *(float2*)&Tl[(b0    ) * 202 + d];
      float2 v1 = *(float2*)&Tl[(b0 + 1) * 202 + d];
      float2 v2 = *(float2*)&Tl[(b0 + 2) * 202 + d];
      float2 v3 = *(float2*)&Tl[(b0 + 3) * 202 + d];
      d0 += va.x * v0.x + va.y * v0.y;
      d1 += va.x * v1.x + va.y * v1.y;
      d2 += va.x * v2.x + va.y * v2.y;
      d3 += va.x * v3.x + va.y * v3.y;
    }
    float na = nrm[a], gg = 0.f, g;
    g = d0 / (na * nrm[b0    ]) - (a == b0     ? 1.f : 0.f); gg += g * g;
    g = d1 / (na * nrm[b0 + 1]) - (a == b0 + 1 ? 1.f : 0.f); gg += g * g;
    g = d2 / (na * nrm[b0 + 2]) - (a == b0 + 2 ? 1.f : 0.f); gg += g * g;
    g = d3 / (na * nrm[b0 + 3]) - (a == b0 + 3 ? 1.f : 0.f); gg += g * g;
    float v = sum64(gg);
    if (j == 63) wred[w] = v;
    __syncthreads();
    if (t == 0){
      atomicAdd(&acc[1], (wred[0] + wred[1] + wred[2] + wred[3]) / (float)(AA * AA));
      __threadfence();
      int prev = atomicAdd((int*)acc + 8, 1);
      if (prev == BB) finalize(acc, out);
    }
    return;
  }

  // ================= segment-mean + rating =================
  int*   idxs = (int*)smem;        // 32
  float* wred = smem + 32;         // 4
  if (t < 16) idxs[t] = u_idx[b * 16 + t];
  else if (t < 32) idxs[t] = i_idx[b * 16 + (t - 16)];
  __syncthreads();
  float su = 0.f, si = 0.f;
  if (t < DD){
#pragma unroll
    for (int k = 0; k < 16; ++k) su += rs[(size_t)idxs[k] * DD + t];
#pragma unroll
    for (int k = 0; k < 16; ++k) si += rs[(size_t)idxs[16 + k] * DD + t];
  }
  float v = sum64(su * si);
  if (j == 63) wred[w] = v;
  __syncthreads();
  if (t == 0){
    float dot = wred[0] + wred[1] + wred[2] + wred[3];
    float pred = dot * (1.f / 256.f) + 3.5f;     // /16 /16
    float e = pred - label[b];
    atomicAdd(&acc[2], e * e);
    __threadfence();
    int prev = atomicAdd((int*)acc + 8, 1);
    if (prev == BB) finalize(acc, out);
  }
}

extern "C" void kernel_launch(void* const* d_in, const int* in_sizes, int n_in,
                              void* d_out, int out_size, void* d_ws, size_t ws_size,
                              hipStream_t stream){
  const int*   hist     = (const int*)  d_in[0];
  const float* rev_pos  = (const float*)d_in[1];
  const float* rev_neg  = (const float*)d_in[2];
  const float* label    = (const float*)d_in[5];
  const int*   u_idx    = (const int*)  d_in[6];
  const int*   i_idx    = (const int*)  d_in[8];
  const float* word_emb = (const float*)d_in[10];
  const float* M_w      = (const float*)d_in[11];
  const float* W_w      = (const float*)d_in[12];
  const float* W_b      = (const float*)d_in[13];
  const float* T_w      = (const float*)d_in[14];

  float* ws   = (float*)d_ws;
  float* rs   = ws + WS_RS;
  float* accp = ws + WS_ACC;

  hipMemsetAsync(accp, 0, 64, stream);   // zero J/U/RL accumulators + counter
  k_main<<<NN, 512, 0, stream>>>(hist, rev_pos, rev_neg, word_emb, M_w,
                                 W_w, W_b, T_w, rs, accp);
  k_tail<<<BB + 1, 256, 0, stream>>>(u_idx, i_idx, rs, label, T_w, accp,
                                     (float*)d_out);
}

// Round 5
// 252.182 us; speedup vs baseline: 1.3225x; 1.3225x over previous
//
#include <hip/hip_runtime.h>

#define NN 4096      // reviews
#define LL 128       // tokens
#define DD 200       // word dim
#define AA 32        // aspects
#define NEG 5
#define BB 1024      // users/items

// workspace layout (float offsets)
// rs region doubles as y region: k_y writes y[n]; k_main block n reads y[n]
// early and overwrites with r_s[n] late (disjoint rows across blocks -> safe).
#define WS_RS    0
#define WS_ACC   (NN*DD)   // [0]=J_sum [1]=U_mean [2]=RL_sum [8]=done(int)

// ---------------- DPP reductions (VALU, no DS pipe) -------------------------
template<int C, int RM>
__device__ __forceinline__ float dpp_add(float v){
  int t = __builtin_amdgcn_update_dpp(0, __float_as_int(v), C, RM, 0xf, false);
  return v + __int_as_float(t);
}
template<int C, int RM>
__device__ __forceinline__ float dpp_fmax(float v){
  int t = __builtin_amdgcn_update_dpp(__float_as_int(-3.0e38f), __float_as_int(v),
                                      C, RM, 0xf, false);
  return fmaxf(v, __int_as_float(t));
}
// full 64-lane sum; valid in lane 63
__device__ __forceinline__ float sum64(float v){
  v = dpp_add<0xB1, 0xF>(v);
  v = dpp_add<0x4E, 0xF>(v);
  v = dpp_add<0x124,0xF>(v);
  v = dpp_add<0x128,0xF>(v);
  v = dpp_add<0x142,0xA>(v);
  v = dpp_add<0x143,0xC>(v);
  return v;
}
__device__ __forceinline__ float max64(float v){
  v = dpp_fmax<0xB1, 0xF>(v);
  v = dpp_fmax<0x4E, 0xF>(v);
  v = dpp_fmax<0x124,0xF>(v);
  v = dpp_fmax<0x128,0xF>(v);
  v = dpp_fmax<0x142,0xA>(v);
  v = dpp_fmax<0x143,0xC>(v);
  return v;
}
// quad (4-lane) sum: valid in all 4 lanes of each quad
__device__ __forceinline__ float sum4(float v){
  v = dpp_add<0xB1, 0xF>(v);    // quad_perm [1,0,3,2]
  v = dpp_add<0x4E, 0xF>(v);    // quad_perm [2,3,0,1]
  return v;
}
__device__ __forceinline__ float rdlane(float v, int l){
  return __int_as_float(__builtin_amdgcn_readlane(__float_as_int(v), l));
}

// ---- y = rp @ M pre-kernel: 16 reviews/block, 4 per wave -------------------
// Shares one 160KB M sweep across 16 reviews (~41 MB M traffic total).
__global__ __launch_bounds__(256)
void k_y(const float* __restrict__ rp, const float* __restrict__ M_w,
         float* __restrict__ y_out){
  __shared__ float rpl[16 * DD];
  const int t = threadIdx.x, j = t & 63;
  const int wu = __builtin_amdgcn_readfirstlane(t >> 6);
  const int n0 = blockIdx.x * 16;
  for (int i = t; i < 16 * DD; i += 256) rpl[i] = rp[(size_t)n0 * DD + i];
  __syncthreads();
  if (j < 50){
    const float4* M4 = (const float4*)M_w + j;   // M_w[k*200 + 4j]
    const float* r0 = rpl + (4*wu + 0) * DD;
    const float* r1 = rpl + (4*wu + 1) * DD;
    const float* r2 = rpl + (4*wu + 2) * DD;
    const float* r3 = rpl + (4*wu + 3) * DD;
    float4 a0 = make_float4(0,0,0,0), a1 = a0, a2 = a0, a3 = a0;
#pragma unroll 4
    for (int k = 0; k < DD; ++k){
      float4 m = M4[k * 50];
      float b0 = r0[k], b1 = r1[k], b2 = r2[k], b3 = r3[k];
      a0.x = fmaf(b0,m.x,a0.x); a0.y = fmaf(b0,m.y,a0.y);
      a0.z = fmaf(b0,m.z,a0.z); a0.w = fmaf(b0,m.w,a0.w);
      a1.x = fmaf(b1,m.x,a1.x); a1.y = fmaf(b1,m.y,a1.y);
      a1.z = fmaf(b1,m.z,a1.z); a1.w = fmaf(b1,m.w,a1.w);
      a2.x = fmaf(b2,m.x,a2.x); a2.y = fmaf(b2,m.y,a2.y);
      a2.z = fmaf(b2,m.z,a2.z); a2.w = fmaf(b2,m.w,a2.w);
      a3.x = fmaf(b3,m.x,a3.x); a3.y = fmaf(b3,m.y,a3.y);
      a3.z = fmaf(b3,m.z,a3.z); a3.w = fmaf(b3,m.w,a3.w);
    }
    const int nb = n0 + 4*wu;
    *(float4*)(y_out + (size_t)(nb+0) * DD + 4*j) = a0;
    *(float4*)(y_out + (size_t)(nb+1) * DD + 4*j) = a1;
    *(float4*)(y_out + (size_t)(nb+2) * DD + 4*j) = a2;
    *(float4*)(y_out + (size_t)(nb+3) * DD + 4*j) = a3;
  }
}

// ---- main per-review kernel ------------------------------------------------
// 512 threads, one review/block, 2 blocks/CU (VGPR-bound; LDS ~3 KB).
// e_w slab held in REGISTERS in z-order: thread t owns flat floats
// [50t, 50t+50) (= token lq=t>>2, cols [50c,50c+50), c=t&3), loaded as 25
// independent dwordx2 with no interleaved VALU -> max MLP.
// dx  = quad-reduce of per-lane 50-dot with y (LDS broadcast).
// z   = per-thread predicated partials into <=2 adjacent d2 windows,
//       accumulated via LDS float atomics (zsm zeroed up front).
__global__ __launch_bounds__(512, 4)
void k_main(const int* __restrict__ hist, const float* __restrict__ rev_neg,
            const float* __restrict__ word_emb, const float* __restrict__ W_w,
            const float* __restrict__ W_b, const float* __restrict__ T_w,
            float* __restrict__ yrs, float* __restrict__ acc)
{
  __shared__ __align__(16) float y_l[DD];
  __shared__ __align__(16) float dxax[LL];
  __shared__ __align__(16) float zsm[DD];
  __shared__ __align__(16) float r_l[DD];
  __shared__ float lsps[AA];
  __shared__ float sc[8];

  const int n = blockIdx.x, t = threadIdx.x;
  const int w = t >> 6, j = t & 63;
  const int wu = __builtin_amdgcn_readfirstlane(w);

  if (t < DD){ y_l[t] = yrs[(size_t)n * DD + t]; zsm[t] = 0.f; }

  // ---- register slab load: 25 independent float2 per thread ---------------
  const int lq = t >> 2, c = t & 3;
  const int row = hist[n * LL + lq];
  float2 e2[25];
  {
    const float2* src = (const float2*)(word_emb + (size_t)row * DD) + c * 25;
#pragma unroll
    for (int i = 0; i < 25; ++i) e2[i] = src[i];
  }
  __syncthreads();

  // ---- dx[lq] = dot(e_w[lq], y): quad c=0..3 covers cols [50c,50c+50) -----
  {
    const int c50 = c * 50;
    float p = 0.f;
#pragma unroll
    for (int i = 0; i < 25; ++i){
      float2 yv = *(const float2*)&y_l[c50 + 2 * i];
      p = fmaf(e2[i].x, yv.x, p);
      p = fmaf(e2[i].y, yv.y, p);
    }
    p = sum4(p);
    if (c == 0) dxax[lq] = p;
  }
  __syncthreads();

  // ---- softmax over 128 logits (wave 0) -----------------------------------
  if (w == 0){
    float a0 = dxax[j], a1 = dxax[j + 64];
    float M = rdlane(max64(fmaxf(a0, a1)), 63);
    float e0 = __expf(a0 - M), e1 = __expf(a1 - M);
    float S = rdlane(sum64(e0 + e1), 63);
    float inv = 1.f / S;
    dxax[j] = e0 * inv; dxax[j + 64] = e1 * inv;
  }
  __syncthreads();

  // ---- z: thread's 50 flat floats -> <=2 adjacent d2 windows --------------
  {
    const int f0 = 50 * t;                 // global flat index of elem 0
    const int d2a = f0 >> 7;
    const int split = ((d2a + 1) << 7) - f0;   // elems < split go to d2a
    float pa = 0.f, pb = 0.f;
#pragma unroll
    for (int cc = 0; cc < 5; ++cc){
      float2 wx[5];
#pragma unroll
      for (int i = 0; i < 5; ++i)
        wx[i] = *(const float2*)&dxax[(f0 + 2 * (5*cc + i)) & 127];
#pragma unroll
      for (int i = 0; i < 5; ++i){
        const int i2 = 2 * (5*cc + i);
        float s0 = e2[5*cc + i].x * wx[i].x;
        float s1 = e2[5*cc + i].y * wx[i].y;
        pa += (i2     < split) ? s0 : 0.f;
        pb += (i2     < split) ? 0.f : s0;
        pa += (i2 + 1 < split) ? s1 : 0.f;
        pb += (i2 + 1 < split) ? 0.f : s1;
      }
    }
    atomicAdd(&zsm[d2a], pa);
    if (split < 50) atomicAdd(&zsm[d2a + 1], pb);
  }
  __syncthreads();

  // ---- aspect logits: wave w computes a = 4w..4w+3 ------------------------
#pragma unroll
  for (int aa = 0; aa < 4; ++aa){
    int a = wu * 4 + aa;
    const float* Wr = W_w + a * DD;
    float p = zsm[j] * Wr[j] + zsm[j + 64] * Wr[j + 64] + zsm[j + 128] * Wr[j + 128];
    if (j < 8) p += zsm[j + 192] * Wr[j + 192];
    float v = sum64(p);
    if (j == 63) lsps[a] = v + W_b[a];
  }
  __syncthreads();

  // ---- softmax over 32 aspects (wave 0) -----------------------------------
  if (w == 0){
    float v = (j < 32) ? lsps[j] : -3.0e38f;
    float M = rdlane(max64(v), 63);
    float e = __expf(v - M);
    float S = rdlane(sum64(e), 63);
    if (j < 32) lsps[j] = e / S;
  }
  __syncthreads();

  // ---- r_s[d] = sum_a p[a]*T_w[d][a]; overwrites y region (safe) ----------
  if (t < DD){
    const float4* Tq = (const float4*)(T_w + t * AA);
    float a = 0.f;
#pragma unroll
    for (int q = 0; q < 8; ++q){
      float4 tv = Tq[q];
      a += lsps[4*q]*tv.x + lsps[4*q+1]*tv.y + lsps[4*q+2]*tv.z + lsps[4*q+3]*tv.w;
    }
    r_l[t] = a;
    yrs[(size_t)n * DD + t] = a;
  }
  __syncthreads();

  // ---- c1 = cos(r, z) (wave 0, float4) ------------------------------------
  if (w == 0){
    float rr = 0, zz = 0, rz = 0;
    if (j < 50){
      float4 rv = *(float4*)(r_l + 4 * j);
      float4 zv = *(float4*)(zsm + 4 * j);
      rr = rv.x*rv.x + rv.y*rv.y + rv.z*rv.z + rv.w*rv.w;
      zz = zv.x*zv.x + zv.y*zv.y + zv.z*zv.z + zv.w*zv.w;
      rz = rv.x*zv.x + rv.y*zv.y + rv.z*zv.z + rv.w*zv.w;
    }
    rr = rdlane(sum64(rr), 63); zz = rdlane(sum64(zz), 63); rz = rdlane(sum64(rz), 63);
    if (j == 0){
      float nr = fmaxf(sqrtf(rr), 1e-12f);
      float nz = fmaxf(sqrtf(zz), 1e-12f);
      sc[0] = rz / (nr * nz);          // c1
      sc[1] = nr;
    }
  }
  __syncthreads();

  // ---- c2 over 5 negatives (waves 0..4), float4 ---------------------------
  if (w < NEG){
    const float* neg = rev_neg + ((size_t)n * NEG + w) * DD;
    float nn = 0, dr = 0;
    if (j < 50){
      float4 v = *(const float4*)(neg + 4 * j);
      float4 rv = *(float4*)(r_l + 4 * j);
      nn = v.x*v.x + v.y*v.y + v.z*v.z + v.w*v.w;
      dr = v.x*rv.x + v.y*rv.y + v.z*rv.z + v.w*rv.w;
    }
    nn = rdlane(sum64(nn), 63); dr = rdlane(sum64(dr), 63);
    if (j == 0){
      float c2 = dr / (fmaxf(sqrtf(nn), 1e-12f) * sc[1]);
      sc[2 + w] = fmaxf(0.f, c2 - sc[0]);
    }
  }
  __syncthreads();
  if (t == 0) atomicAdd(&acc[0], sc[2] + sc[3] + sc[4] + sc[5] + sc[6]);
}

// ---- finalize helper -------------------------------------------------------
__device__ __forceinline__ void finalize(float* acc, float* out){
  float R = atomicAdd(&acc[2], 0.f) / (float)BB;        // coherent reads
  float J = atomicAdd(&acc[0], 0.f) / (float)(NN * NEG);
  float U = atomicAdd(&acc[1], 0.f);
  out[0] = R + U + J;
  out[1] = R;
  out[2] = U + J;
}

// ---- tail: blocks 0..BB-1 = segment-mean + rating; block BB = U loss -------
// seg ids are repeat(arange(B), H=16): block b owns entries [16b,16b+16).
__global__ __launch_bounds__(256)
void k_tail(const int* __restrict__ u_idx, const int* __restrict__ i_idx,
            const float* __restrict__ rs, const float* __restrict__ label,
            const float* __restrict__ T_w, float* __restrict__ acc,
            float* __restrict__ out){
  __shared__ __align__(16) float smem[6500];
  const int b = blockIdx.x, t = threadIdx.x, w = t >> 6, j = t & 63;

  if (b == BB){
    // ================= U loss =================
    float* Tl  = smem;          // [32][202]
    float* nrm = smem + 6464;
    float* wred= smem + 6496;
    for (int i = t; i < DD * AA; i += 256){
      int d = i >> 5, a = i & 31;
      Tl[a * 202 + d] = T_w[i];
    }
    __syncthreads();
    if (t < AA){
      float s = 0.f;
      for (int d = 0; d < DD; d += 2){
        float2 v = *(float2*)&Tl[t * 202 + d];
        s += v.x * v.x + v.y * v.y;
      }
      nrm[t] = fmaxf(sqrtf(s), 1e-12f);
    }
    __syncthreads();
    int a = t >> 3, b0 = (t & 7) * 4;
    float d0 = 0, d1 = 0, d2 = 0, d3 = 0;
    for (int d = 0; d < DD; d += 2){
      float2 va = *(float2*)&Tl[a * 202 + d];
      float2 v0 = *(float2*)&Tl[(b0    ) * 202 + d];
      float2 v1 = *(float2*)&Tl[(b0 + 1) * 202 + d];
      float2 v2 = *(float2*)&Tl[(b0 + 2) * 202 + d];
      float2 v3 = *(float2*)&Tl[(b0 + 3) * 202 + d];
      d0 += va.x * v0.x + va.y * v0.y;
      d1 += va.x * v1.x + va.y * v1.y;
      d2 += va.x * v2.x + va.y * v2.y;
      d3 += va.x * v3.x + va.y * v3.y;
    }
    float na = nrm[a], gg = 0.f, g;
    g = d0 / (na * nrm[b0    ]) - (a == b0     ? 1.f : 0.f); gg += g * g;
    g = d1 / (na * nrm[b0 + 1]) - (a == b0 + 1 ? 1.f : 0.f); gg += g * g;
    g = d2 / (na * nrm[b0 + 2]) - (a == b0 + 2 ? 1.f : 0.f); gg += g * g;
    g = d3 / (na * nrm[b0 + 3]) - (a == b0 + 3 ? 1.f : 0.f); gg += g * g;
    float v = sum64(gg);
    if (j == 63) wred[w] = v;
    __syncthreads();
    if (t == 0){
      atomicAdd(&acc[1], (wred[0] + wred[1] + wred[2] + wred[3]) / (float)(AA * AA));
      __threadfence();
      int prev = atomicAdd((int*)acc + 8, 1);
      if (prev == BB) finalize(acc, out);
    }
    return;
  }

  // ================= segment-mean + rating =================
  int*   idxs = (int*)smem;        // 32
  float* wred = smem + 32;         // 4
  if (t < 16) idxs[t] = u_idx[b * 16 + t];
  else if (t < 32) idxs[t] = i_idx[b * 16 + (t - 16)];
  __syncthreads();
  float su = 0.f, si = 0.f;
  if (t < DD){
#pragma unroll
    for (int k = 0; k < 16; ++k) su += rs[(size_t)idxs[k] * DD + t];
#pragma unroll
    for (int k = 0; k < 16; ++k) si += rs[(size_t)idxs[16 + k] * DD + t];
  }
  float v = sum64(su * si);
  if (j == 63) wred[w] = v;
  __syncthreads();
  if (t == 0){
    float dot = wred[0] + wred[1] + wred[2] + wred[3];
    float pred = dot * (1.f / 256.f) + 3.5f;     // /16 /16
    float e = pred - label[b];
    atomicAdd(&acc[2], e * e);
    __threadfence();
    int prev = atomicAdd((int*)acc + 8, 1);
    if (prev == BB) finalize(acc, out);
  }
}

extern "C" void kernel_launch(void* const* d_in, const int* in_sizes, int n_in,
                              void* d_out, int out_size, void* d_ws, size_t ws_size,
                              hipStream_t stream){
  const int*   hist     = (const int*)  d_in[0];
  const float* rev_pos  = (const float*)d_in[1];
  const float* rev_neg  = (const float*)d_in[2];
  const float* label    = (const float*)d_in[5];
  const int*   u_idx    = (const int*)  d_in[6];
  const int*   i_idx    = (const int*)  d_in[8];
  const float* word_emb = (const float*)d_in[10];
  const float* M_w      = (const float*)d_in[11];
  const float* W_w      = (const float*)d_in[12];
  const float* W_b      = (const float*)d_in[13];
  const float* T_w      = (const float*)d_in[14];

  float* ws   = (float*)d_ws;
  float* yrs  = ws + WS_RS;      // y first, then r_s (aliased, see header note)
  float* accp = ws + WS_ACC;

  hipMemsetAsync(accp, 0, 64, stream);   // zero J/U/RL accumulators + counter
  k_y   <<<NN / 16, 256, 0, stream>>>(rev_pos, M_w, yrs);
  k_main<<<NN, 512, 0, stream>>>(hist, rev_neg, word_emb, W_w, W_b, T_w,
                                 yrs, accp);
  k_tail<<<BB + 1, 256, 0, stream>>>(u_idx, i_idx, yrs, label, T_w, accp,
                                     (float*)d_out);
}